// Round 1
// baseline (223.731 us; speedup 1.0000x reference)
//
#include <hip/hip_runtime.h>

#define NBLOCKS 1024
#define NTHREADS 256

__device__ __forceinline__ float wave_reduce_sum(float v) {
#pragma unroll
    for (int off = 32; off > 0; off >>= 1)
        v += __shfl_down(v, off, 64);
    return v;
}

// quat2mat per reference:
// r00 = q0^2+q1^2-q2^2-q3^2 ; r01 = 2(q1q2-q0q3) ; r02 = 2(q1q3+q0q2)
// r10 = 2(q1q2+q0q3)        ; r11 = q0^2-q1^2+q2^2-q3^2 ; r12 = 2(q2q3-q0q1)
// r20 = 2(q1q3-q0q2)        ; r21 = 2(q2q3+q0q1) ; r22 = q0^2-q1^2-q2^2+q3^2
__device__ __forceinline__ void quat2mat(float q0, float q1, float q2, float q3,
                                         float m[9]) {
    float q00 = q0 * q0, q11 = q1 * q1, q22 = q2 * q2, q33 = q3 * q3;
    m[0] = q00 + q11 - q22 - q33;
    m[1] = 2.0f * (q1 * q2 - q0 * q3);
    m[2] = 2.0f * (q1 * q3 + q0 * q2);
    m[3] = 2.0f * (q1 * q2 + q0 * q3);
    m[4] = q00 - q11 + q22 - q33;
    m[5] = 2.0f * (q2 * q3 - q0 * q1);
    m[6] = 2.0f * (q1 * q3 - q0 * q2);
    m[7] = 2.0f * (q2 * q3 + q0 * q1);
    m[8] = q00 - q11 - q22 + q33;
}

__global__ __launch_bounds__(NTHREADS) void hpnet_loss_kernel(
    const float* __restrict__ conf,     // (B,1,H,W) flat = 16777216
    const float* __restrict__ conf_gt,  // same
    const float* __restrict__ weight,   // (B,H,W) flat = 16777216
    const float* __restrict__ dr,       // (N,5)
    const float* __restrict__ ann,      // (N,5)
    const int*   __restrict__ flags,    // (N,) bool->int32
    float* __restrict__ out,            // [3] : conf_loss, depth_loss, rot_loss
    long long n_conf, int N) {
    const long long gid = (long long)blockIdx.x * blockDim.x + threadIdx.x;
    const long long gstride = (long long)gridDim.x * blockDim.x;

    // ---- Part 1: confidence loss (HBM-bound bulk) -------------------------
    const float4* __restrict__ c4 = (const float4*)conf;
    const float4* __restrict__ g4 = (const float4*)conf_gt;
    const float4* __restrict__ w4 = (const float4*)weight;
    const long long n4 = n_conf >> 2;  // 16777216 / 4 = 4194304

    float acc_c = 0.0f;
    for (long long i = gid; i < n4; i += gstride) {
        float4 c = c4[i];
        float4 g = g4[i];
        float4 w = w4[i];
        float d0 = c.x - g.x, d1 = c.y - g.y, d2 = c.z - g.z, d3 = c.w - g.w;
        acc_c += w.x * d0 * d0 + w.y * d1 * d1 + w.z * d2 * d2 + w.w * d3 * d3;
    }

    // ---- Part 2 + 3: depth & rotation losses (tiny) -----------------------
    float acc_d = 0.0f;
    float acc_r = 0.0f;
    for (long long n = gid; n < N; n += gstride) {
        float m = flags[n] ? 1.0f : 0.0f;

        // depth
        float de = dr[n * 5 + 0] - ann[n * 5 + 0];
        acc_d += m * de * de;

        // m_pred from ann quaternion (NOT normalized, per reference)
        float mp[9];
        quat2mat(ann[n * 5 + 1], ann[n * 5 + 2], ann[n * 5 + 3], ann[n * 5 + 4], mp);

        // m_gt from normalized dr quaternion
        float p0 = dr[n * 5 + 1], p1 = dr[n * 5 + 2], p2 = dr[n * 5 + 3],
              p3 = dr[n * 5 + 4];
        float inv = 1.0f / sqrtf(p0 * p0 + p1 * p1 + p2 * p2 + p3 * p3);
        float mg[9];
        quat2mat(p0 * inv, p1 * inv, p2 * inv, p3 * inv, mg);

        // n1 = ||mg - mp||_F ; n2 = ||mg - mp@RY||_F, RY = diag(-1,1,-1)
        // (m @ diag(-1,1,-1)) negates columns 0 and 2
        float s1 = 0.0f, s2 = 0.0f;
#pragma unroll
        for (int r = 0; r < 3; ++r) {
            float a0 = mg[r * 3 + 0], a1 = mg[r * 3 + 1], a2 = mg[r * 3 + 2];
            float b0 = mp[r * 3 + 0], b1 = mp[r * 3 + 1], b2 = mp[r * 3 + 2];
            float e0 = a0 - b0, e1 = a1 - b1, e2 = a2 - b2;
            s1 += e0 * e0 + e1 * e1 + e2 * e2;
            float f0 = a0 + b0, f2 = a2 + b2;  // gt - (-pred_col)
            s2 += f0 * f0 + e1 * e1 + f2 * f2;
        }
        acc_r += m * fminf(sqrtf(s1), sqrtf(s2));
    }

    // ---- Reductions: wave -> LDS -> block -> atomic -----------------------
    acc_c = wave_reduce_sum(acc_c);
    acc_d = wave_reduce_sum(acc_d);
    acc_r = wave_reduce_sum(acc_r);

    __shared__ float s_c[NTHREADS / 64], s_d[NTHREADS / 64], s_r[NTHREADS / 64];
    const int lane = threadIdx.x & 63;
    const int wid = threadIdx.x >> 6;
    if (lane == 0) {
        s_c[wid] = acc_c;
        s_d[wid] = acc_d;
        s_r[wid] = acc_r;
    }
    __syncthreads();
    if (threadIdx.x == 0) {
        float tc = 0.0f, td = 0.0f, tr = 0.0f;
#pragma unroll
        for (int w = 0; w < NTHREADS / 64; ++w) {
            tc += s_c[w];
            td += s_d[w];
            tr += s_r[w];
        }
        atomicAdd(&out[0], tc * (1.0f / (256.0f * 256.0f)));
        atomicAdd(&out[1], td * (1.0f / 8192.0f));
        atomicAdd(&out[2], tr * (1.0f / 8192.0f));
    }
}

extern "C" void kernel_launch(void* const* d_in, const int* in_sizes, int n_in,
                              void* d_out, int out_size, void* d_ws,
                              size_t ws_size, hipStream_t stream) {
    const float* conf    = (const float*)d_in[0];
    const float* conf_gt = (const float*)d_in[1];
    const float* weight  = (const float*)d_in[2];
    const float* dr      = (const float*)d_in[3];
    const float* ann     = (const float*)d_in[4];
    const int*   flags   = (const int*)d_in[5];
    float* out = (float*)d_out;

    const long long n_conf = (long long)in_sizes[0];  // 16777216
    const int N = in_sizes[5];                        // 8192

    // d_out is poisoned to 0xAA before every timed launch — zero it first.
    hipMemsetAsync(d_out, 0, 3 * sizeof(float), stream);

    hpnet_loss_kernel<<<NBLOCKS, NTHREADS, 0, stream>>>(
        conf, conf_gt, weight, dr, ann, flags, out, n_conf, N);
}

// Round 2
// 203.528 us; speedup vs baseline: 1.0993x; 1.0993x over previous
//
#include <hip/hip_runtime.h>

#define NBLOCKS 2048
#define NTHREADS 256

__device__ __forceinline__ float wave_reduce_sum(float v) {
#pragma unroll
    for (int off = 32; off > 0; off >>= 1)
        v += __shfl_down(v, off, 64);
    return v;
}

// quat2mat per reference (row-major 3x3)
__device__ __forceinline__ void quat2mat(float q0, float q1, float q2, float q3,
                                         float m[9]) {
    float q00 = q0 * q0, q11 = q1 * q1, q22 = q2 * q2, q33 = q3 * q3;
    m[0] = q00 + q11 - q22 - q33;
    m[1] = 2.0f * (q1 * q2 - q0 * q3);
    m[2] = 2.0f * (q1 * q3 + q0 * q2);
    m[3] = 2.0f * (q1 * q2 + q0 * q3);
    m[4] = q00 - q11 + q22 - q33;
    m[5] = 2.0f * (q2 * q3 - q0 * q1);
    m[6] = 2.0f * (q1 * q3 - q0 * q2);
    m[7] = 2.0f * (q2 * q3 + q0 * q1);
    m[8] = q00 - q11 - q22 + q33;
}

// Per-block 3-way block reduction -> dst[0..2]
__device__ __forceinline__ void block_reduce3(float c, float d, float r,
                                              float* dst) {
    c = wave_reduce_sum(c);
    d = wave_reduce_sum(d);
    r = wave_reduce_sum(r);
    __shared__ float s_c[NTHREADS / 64], s_d[NTHREADS / 64], s_r[NTHREADS / 64];
    const int lane = threadIdx.x & 63;
    const int wid = threadIdx.x >> 6;
    if (lane == 0) {
        s_c[wid] = c;
        s_d[wid] = d;
        s_r[wid] = r;
    }
    __syncthreads();
    if (threadIdx.x == 0) {
        float tc = 0.0f, td = 0.0f, tr = 0.0f;
#pragma unroll
        for (int w = 0; w < NTHREADS / 64; ++w) {
            tc += s_c[w];
            td += s_d[w];
            tr += s_r[w];
        }
        dst[0] = tc;
        dst[1] = td;
        dst[2] = tr;
    }
}

__global__ __launch_bounds__(NTHREADS) void hpnet_partial_kernel(
    const float* __restrict__ conf, const float* __restrict__ conf_gt,
    const float* __restrict__ weight, const float* __restrict__ dr,
    const float* __restrict__ ann, const int* __restrict__ flags,
    float* __restrict__ part,  // (NBLOCKS, 3)
    long long n_conf, int N) {
    const long long gid = (long long)blockIdx.x * blockDim.x + threadIdx.x;
    const long long gstride = (long long)gridDim.x * blockDim.x;

    // ---- Part 1: confidence loss (BW/latency-bound bulk) ------------------
    const float4* __restrict__ c4 = (const float4*)conf;
    const float4* __restrict__ g4 = (const float4*)conf_gt;
    const float4* __restrict__ w4 = (const float4*)weight;
    const long long n4 = n_conf >> 2;  // 4194304

    float acc_a = 0.0f, acc_b = 0.0f;
    // unroll x2 with independent accumulators for MLP
    for (long long i = gid; i < n4; i += 2 * gstride) {
        float4 c0 = c4[i];
        float4 g0 = g4[i];
        float4 w0 = w4[i];
        long long j = i + gstride;
        if (j < n4) {
            float4 c1 = c4[j];
            float4 g1 = g4[j];
            float4 w1 = w4[j];
            float d0 = c1.x - g1.x, d1 = c1.y - g1.y, d2 = c1.z - g1.z,
                  d3 = c1.w - g1.w;
            acc_b += w1.x * d0 * d0 + w1.y * d1 * d1 + w1.z * d2 * d2 +
                     w1.w * d3 * d3;
        }
        float d0 = c0.x - g0.x, d1 = c0.y - g0.y, d2 = c0.z - g0.z,
              d3 = c0.w - g0.w;
        acc_a += w0.x * d0 * d0 + w0.y * d1 * d1 + w0.z * d2 * d2 +
                 w0.w * d3 * d3;
    }
    float acc_c = acc_a + acc_b;

    // ---- Part 2 + 3: depth & rotation losses (tiny) -----------------------
    float acc_d = 0.0f;
    float acc_r = 0.0f;
    for (long long n = gid; n < N; n += gstride) {
        float m = flags[n] ? 1.0f : 0.0f;

        float de = dr[n * 5 + 0] - ann[n * 5 + 0];
        acc_d += m * de * de;

        float mp[9];
        quat2mat(ann[n * 5 + 1], ann[n * 5 + 2], ann[n * 5 + 3],
                 ann[n * 5 + 4], mp);

        float p0 = dr[n * 5 + 1], p1 = dr[n * 5 + 2], p2 = dr[n * 5 + 3],
              p3 = dr[n * 5 + 4];
        float inv = 1.0f / sqrtf(p0 * p0 + p1 * p1 + p2 * p2 + p3 * p3);
        float mg[9];
        quat2mat(p0 * inv, p1 * inv, p2 * inv, p3 * inv, mg);

        // RY = diag(-1,1,-1): m_pred @ RY negates cols 0 and 2
        float s1 = 0.0f, s2 = 0.0f;
#pragma unroll
        for (int r = 0; r < 3; ++r) {
            float a0 = mg[r * 3 + 0], a1 = mg[r * 3 + 1], a2 = mg[r * 3 + 2];
            float b0 = mp[r * 3 + 0], b1 = mp[r * 3 + 1], b2 = mp[r * 3 + 2];
            float e0 = a0 - b0, e1 = a1 - b1, e2 = a2 - b2;
            s1 += e0 * e0 + e1 * e1 + e2 * e2;
            float f0 = a0 + b0, f2 = a2 + b2;
            s2 += f0 * f0 + e1 * e1 + f2 * f2;
        }
        acc_r += m * fminf(sqrtf(s1), sqrtf(s2));
    }

    block_reduce3(acc_c, acc_d, acc_r, &part[3 * blockIdx.x]);
}

__global__ __launch_bounds__(NTHREADS) void hpnet_final_kernel(
    const float* __restrict__ part,  // (NBLOCKS, 3)
    float* __restrict__ out) {
    float tc = 0.0f, td = 0.0f, tr = 0.0f;
    for (int i = threadIdx.x; i < NBLOCKS; i += NTHREADS) {
        tc += part[3 * i + 0];
        td += part[3 * i + 1];
        tr += part[3 * i + 2];
    }
    __shared__ float dst[3];
    block_reduce3(tc, td, tr, dst);
    __syncthreads();
    if (threadIdx.x == 0) {
        out[0] = dst[0] * (1.0f / (256.0f * 256.0f));
        out[1] = dst[1] * (1.0f / 8192.0f);
        out[2] = dst[2] * (1.0f / 8192.0f);
    }
}

extern "C" void kernel_launch(void* const* d_in, const int* in_sizes, int n_in,
                              void* d_out, int out_size, void* d_ws,
                              size_t ws_size, hipStream_t stream) {
    const float* conf    = (const float*)d_in[0];
    const float* conf_gt = (const float*)d_in[1];
    const float* weight  = (const float*)d_in[2];
    const float* dr      = (const float*)d_in[3];
    const float* ann     = (const float*)d_in[4];
    const int*   flags   = (const int*)d_in[5];
    float* out = (float*)d_out;
    float* part = (float*)d_ws;  // NBLOCKS*3 floats

    const long long n_conf = (long long)in_sizes[0];  // 16777216
    const int N = in_sizes[5];                        // 8192

    hpnet_partial_kernel<<<NBLOCKS, NTHREADS, 0, stream>>>(
        conf, conf_gt, weight, dr, ann, flags, part, n_conf, N);
    hpnet_final_kernel<<<1, NTHREADS, 0, stream>>>(part, out);
}